// Round 4
// baseline (650.479 us; speedup 1.0000x reference)
//
#include <hip/hip_runtime.h>
#include <stdint.h>

// Problem constants (match reference)
#define BB     4
#define CC     32
#define HH     32
#define WW     1024
#define PATCH  21
#define DIL    2
#define RAD    10
#define PADW   20                 // DIL*RAD : max displacement
#define CHUNKC 4                  // channels staged per pass
#define NP     (CC / CHUNKC)      // 8 passes
#define NGR    266                // float4 granules per padded row ((1024+40)/4)
#define ROWF   (NGR * 4)          // 1064 floats per channel row
#define BUFF   (CHUNKC * ROWF)    // 4256 floats per buffer (17 KB)

// R3 POST-MORTEM: LDS-read bound (3.9 GB ds_read + 1.1 GB DMA writes + 1.1e7
// conflict cycles ~ 106 of 152 us). R4: (a) NT=5..6 taps/thread cuts B/FMA
// 2.0 -> 1.45 (reads 3.9 -> 3.2 GB); (b) ONE staging per (h,bp) via 512-thread
// blocks with 4-way wave-uniform tap split (writes 1.1 -> 0.37 GB, barriers /6);
// (c) sigma2 swizzle kills residual conflicts under BOTH plausible LDS phase
// groupings; (d) XCD-slot block mapping for x2 L2 locality.
typedef __attribute__((address_space(3))) uint32_t lds_u32_t;
typedef __attribute__((address_space(1))) const uint32_t glb_u32_t;

// Involution on granule index. Bank quad of slot s is s%8; sigma2 makes the
// Wout=8 read pattern (slots 2*lane+c .. +NV4) hit 8 distinct quads within any
// 8 consecutive lanes, and <=2-way (free, m136) under strided-8 grouping.
// Closed on the OOB slot set {0..4} u {261..265} (264<->265, rest fixed).
__device__ __forceinline__ int swz(int s) {
    return s ^ ((s >> 3) & 1) ^ (((s >> 4) & 3) << 1);
}

// DMA CHUNKC channels of one x2 row into sbuf. LDS dest is linear per slot
// (wave-uniform base + lane*16); the swizzle is realized by fetching global
// granule swz(q) into physical slot q (rule #21: same involution both sides).
// Slots whose logical granule is fully out-of-range keep their prologue zeros.
__device__ __forceinline__ void stage_dma(const float* __restrict__ x2c0,
                                          float* __restrict__ sbuf, int tid) {
#pragma unroll
    for (int t = 0; t < 3; t++) {
        const int idx = tid + t * 512;
        if (idx < CHUNKC * NGR) {
            const int c  = idx / NGR;
            const int q  = idx - c * NGR;
            const int gq = swz(q);
            const int base_gran = (tid & ~63) + t * 512;   // wave-uniform
            lds_u32_t* ldst = (lds_u32_t*)(sbuf + base_gran * 4);
            const float* src = x2c0 + (size_t)c * (HH * WW) + (gq * 4 - PADW);
            if (gq >= 5 && gq <= 260)
                __builtin_amdgcn_global_load_lds((glb_u32_t*)src, ldst, 16, 0, 0);
        }
    }
}

// One pass (CHUNKC channels) of FMA work for a tap group: NT taps from PJ0.
template <int PJ0, int NT>
__device__ __forceinline__ void compute_pass(const float* __restrict__ x1p,
                                             const float* __restrict__ bufc,
                                             const int (&ps)[5],
                                             float (&acc)[6][8]) {
    constexpr int PJ0A = PJ0 & ~1;
    constexpr int DD   = 2 * (PJ0 - PJ0A);                 // 0 or 2
    constexpr int NV4  = (DD + 8 + 2 * (NT - 1) + 3) / 4;  // 5,4,5,4
    static_assert(NV4 <= 5, "ps[] too small");
#pragma unroll
    for (int c = 0; c < CHUNKC; c++) {
        const float* xp = x1p + (size_t)c * (HH * WW);
        float4 a0 = *(const float4*)xp;
        float4 a1 = *(const float4*)(xp + 4);
        const float a[8] = {a0.x, a0.y, a0.z, a0.w, a1.x, a1.y, a1.z, a1.w};
        const float* row = bufc + c * ROWF;
        float win[NV4 * 4];
#pragma unroll
        for (int r = 0; r < NV4; r++)
            *(float4*)&win[4 * r] = *(const float4*)(row + ps[r]);
        // tap PJ0+j, output w8+k  ->  window float DD + k + 2*j (static index)
#pragma unroll
        for (int j = 0; j < NT; j++)
#pragma unroll
            for (int k = 0; k < 8; k++)
                acc[j][k] = fmaf(a[k], win[DD + k + 2 * j], acc[j][k]);
    }
}

template <int NT>
__device__ __forceinline__ void epilogue(float* __restrict__ outp,
                                         const float (&acc)[6][8], float inv_c) {
#pragma unroll
    for (int j = 0; j < NT; j++) {
        float4 o0, o1;
        float* p0 = (float*)&o0;
        float* p1 = (float*)&o1;
#pragma unroll
        for (int k = 0; k < 4; k++) {
            float v0 = acc[j][k] * inv_c;
            float v1 = acc[j][4 + k] * inv_c;
            p0[k] = v0 > 0.f ? v0 : 0.1f * v0;
            p1[k] = v1 > 0.f ? v1 : 0.1f * v1;
        }
        *(float4*)(outp + (size_t)j * HH * WW)     = o0;
        *(float4*)(outp + (size_t)j * HH * WW + 4) = o1;
    }
}

// Block: 512 threads = 128 w-positions (Wout=8) x 4 tap groups.
// Groups (PJ0,NT): (0,6) (6,5) (11,5) (16,5) -- all 21 taps, ONE staging.
__global__ __launch_bounds__(512, 4)
void corr_kernel(const float* __restrict__ x1, const float* __restrict__ x2,
                 float* __restrict__ out) {
    __shared__ float sx2[2 * BUFF];   // 34 KB -> 2 blocks/CU (LDS 68 KB)

    const int tid = threadIdx.x;
    const int tw  = tid & 127;
    const int th4 = tid >> 7;              // tap group, uniform per wave-pair

    // XCD-aware decomposition: blockIdx.x (0..7) is the XCD slot under the
    // linear-id mod-8 round-robin; slot = b*2 + h-half keeps each XCD on a
    // ~6 MB (x1 half + x2[b]) slab for L2 locality. Perf heuristic only.
    const int b   = blockIdx.x >> 1;
    const int hh  = blockIdx.x & 1;
    const int by  = blockIdx.y;            // 0..335
    const int pi  = by % PATCH;
    const int h   = hh * 16 + by / PATCH;
    const int r2  = h + DIL * (pi - RAD);  // x2 source row (same for all taps)
    const int w8  = tw * 8;

    const int PJ0r = (th4 == 0) ? 0 : (th4 == 1) ? 6 : (th4 == 2) ? 11 : 16;
    const int NTr  = (th4 == 0) ? 6 : 5;

    float* outp = out + (((size_t)(b * PATCH * PATCH + pi * PATCH + PJ0r)) * HH + h) * WW + w8;

    if ((unsigned)r2 >= (unsigned)HH) {
        // whole displacement row OOB -> zeros (block-uniform: no barriers run)
        float4 z = make_float4(0.f, 0.f, 0.f, 0.f);
        for (int j = 0; j < NTr; j++) {
            *(float4*)(outp + (size_t)j * HH * WW)     = z;
            *(float4*)(outp + (size_t)j * HH * WW + 4) = z;
        }
        return;
    }

    // Prologue: zero the 10 never-staged (OOB) granules of each of the 8
    // channel-rows (2 buffers x 4 channels). sigma2 keeps this slot set closed.
    if (tid < 80) {
        const int rr = tid / 10, g = tid % 10;
        const int slot = (g < 5) ? g : (256 + g);   // 0..4 / 261..265
        float4 z = make_float4(0.f, 0.f, 0.f, 0.f);
        *(float4*)(sx2 + rr * ROWF + 4 * slot) = z;
    }

    // Physical window slot offsets (floats), static-indexed thereafter.
    const int pj0a2 = (th4 == 0) ? 0 : (th4 == 1) ? 3 : (th4 == 2) ? 5 : 8;
    const int g0 = 2 * tw + pj0a2;
    int ps[5];
#pragma unroll
    for (int r = 0; r < 5; r++) ps[r] = 4 * swz(g0 + r);

    const float* x2base = x2 + ((size_t)(b * CC) * HH + r2) * WW;  // + c*HH*WW
    const float* x1base = x1 + ((size_t)(b * CC) * HH + h) * WW + w8;

    stage_dma(x2base, sx2, tid);      // chunk 0 -> buf 0
    __syncthreads();                  // drains DMA + prologue zeros

    float acc[6][8];
#pragma unroll
    for (int j = 0; j < 6; j++)
#pragma unroll
        for (int k = 0; k < 8; k++) acc[j][k] = 0.f;

    for (int p = 0; p < NP; p++) {
        // issue next chunk's DMA BEFORE computing this one (latency hides
        // under the FMA/LDS phase; pass-end barrier drains it).
        if (p + 1 < NP)
            stage_dma(x2base + (size_t)(p + 1) * CHUNKC * HH * WW,
                      sx2 + ((p + 1) & 1) * BUFF, tid);
        const float* bufc = sx2 + (p & 1) * BUFF;
        const float* x1p  = x1base + (size_t)p * CHUNKC * HH * WW;
        if (th4 == 0)      compute_pass<0,  6>(x1p, bufc, ps, acc);
        else if (th4 == 1) compute_pass<6,  5>(x1p, bufc, ps, acc);
        else if (th4 == 2) compute_pass<11, 5>(x1p, bufc, ps, acc);
        else               compute_pass<16, 5>(x1p, bufc, ps, acc);
        if (p + 1 < NP) __syncthreads();
    }

    const float inv_c = 1.0f / (float)CC;
    if (th4 == 0)      epilogue<6>(outp, acc, inv_c);
    else if (th4 == 1) epilogue<5>(outp, acc, inv_c);
    else if (th4 == 2) epilogue<5>(outp, acc, inv_c);
    else               epilogue<5>(outp, acc, inv_c);
}

extern "C" void kernel_launch(void* const* d_in, const int* in_sizes, int n_in,
                              void* d_out, int out_size, void* d_ws, size_t ws_size,
                              hipStream_t stream) {
    const float* x1 = (const float*)d_in[0];
    const float* x2 = (const float*)d_in[1];
    float* out = (float*)d_out;

    // grid.x = 8 XCD slots (b*2 + h-half), grid.y enumerates (pi, h16).
    dim3 grid(8, (PATCH * 16), 1);   // 8 x 336 = 2688 blocks
    dim3 block(512, 1, 1);
    corr_kernel<<<grid, block, 0, stream>>>(x1, x2, out);
}

// Round 5
// 385.365 us; speedup vs baseline: 1.6880x; 1.6880x over previous
//
#include <hip/hip_runtime.h>
#include <stdint.h>

// Problem constants (match reference)
#define BB     4
#define CC     32
#define HH     32
#define WW     1024
#define PATCH  21
#define RAD    10
#define PADW   20                 // DIL*RAD : max displacement
#define CHUNKC 2                  // channels staged per pass (R3-proven; keeps x1 regs low)
#define NP     (CC / CHUNKC)      // 16 passes
#define NGR    266                // float4 granules per padded row ((1024+40)/4)
#define ROWF   (NGR * 4)          // 1064 floats per channel row
#define BUFF   (CHUNKC * ROWF)    // 2128 floats per buffer (8.5 KB)
#define CSTR   (HH * WW)          // channel stride (also the out pj stride)

// R4 POST-MORTEM: spill again (VGPR=64 vs ~96 need; 745 MB scratch writes).
// R5 keeps R3's proven register envelope (acc=32 AGPR-able, 256 thr, CHUNKC=2,
// single compute instantiation) and cuts LDS reads 2.7x via NPI=2 pi-sharing:
// (h,pi) and (h+2,pi-1) use the SAME x2 row, so one window read feeds both.
typedef __attribute__((address_space(3))) uint32_t lds_u32_t;
typedef __attribute__((address_space(1))) const uint32_t glb_u32_t;

// Involution on granule index: for 8 consecutive even (or odd) logical slots,
// sigma's image is a complete residue system mod 8 -> conflict-free b128 reads.
// Closed on the never-staged OOB slot set {0..4, 261..265} (264<->265).
__device__ __forceinline__ int swz(int s) { return s ^ ((s >> 3) & 1); }

// DMA CHUNKC channels of one x2 row into sbuf (linear LDS dest = wave-uniform
// base + lane*16; swizzle realized by fetching global granule swz(q) into
// physical slot q — rule #21). Fully-OOB granules skipped -> keep prologue zeros.
__device__ __forceinline__ void stage_dma(const float* __restrict__ src0,
                                          float* __restrict__ sbuf, int tid) {
#pragma unroll
    for (int t = 0; t < 3; t++) {
        const int idx = tid + t * 256;
        if (idx < CHUNKC * NGR) {
            const int c  = (idx >= NGR) ? 1 : 0;
            const int q  = idx - c * NGR;
            const int gq = swz(q);
            const int base_gran = (tid & ~63) + t * 256;   // wave-uniform
            lds_u32_t* dst = (lds_u32_t*)(sbuf + base_gran * 4);
            const float* src = src0 + (size_t)c * CSTR + (gq * 4 - PADW);
            if (gq >= 5 && gq <= 260)
                __builtin_amdgcn_global_load_lds((glb_u32_t*)src, dst, 16, 0, 0);
        }
    }
}

// Block: 256 threads = 128 w-positions (Wout=8) x 2 tap-halves.
// Grid: (r2+20 in [0,72), b*8+chainslot, z in [0,6)).
// Chain for fixed (b,r2): elements e -> (pi = pi_hi - e, h = h0 + 2e); a slot
// owns elements {2s, 2s+1} (h rows h0+4s, h0+4s+2) sharing x2 row r2.
// Taps: pj = 4z + 2*th2 + j, j in {0,1}; pjb always EVEN -> one code path.
__global__ __launch_bounds__(256, 5)
void corr_kernel(const float* __restrict__ x1, const float* __restrict__ x2,
                 float* __restrict__ out) {
    __shared__ float sx2[2 * BUFF + 16];   // +16: masked tap-21 over-read pad

    const int tid = threadIdx.x;
    const int tw  = tid & 127;
    const int th2 = tid >> 7;              // wave-uniform (waves 0,1 vs 2,3)
    const int r2  = (int)blockIdx.x - PADW;     // -20..51
    const int b   = blockIdx.y >> 3;
    const int s   = blockIdx.y & 7;             // chain pair-slot
    const int z   = blockIdx.z;

    const int pi_hi = min(20, (r2 + 20) >> 1);
    const int pi_lo = max(0, (r2 - 10) >> 1);   // ceil((r2-11)/2) clamped
    const int L     = pi_hi - pi_lo + 1;        // chain length (1..16)
    const int e0    = 2 * s;
    if (e0 >= L) return;                        // empty slot: uniform exit

    const int  pi0  = pi_hi - e0;
    const int  h0   = r2 + 20 - 2 * pi0;        // in [0,31] by construction
    const bool has1 = (e0 + 1) < L;
    const int  pi1  = pi0 - 1;
    const int  h1   = h0 + 2;

    const int  pjb    = 4 * z + 2 * th2;        // even tap base
    const bool st0    = (pjb     <= 20);        // false only z=5,th2=1
    const bool st1    = (pjb + 1 <= 20);        // false for z=5 (tap 21/23)
    const bool active = st0;                    // inactive waves: stage+barrier only
    const int  w8     = tw * 8;

    float* out0 = out + (((size_t)(b * PATCH * PATCH + pi0 * PATCH + pjb)) * HH + h0) * WW + w8;
    float* out1 = out + (((size_t)(b * PATCH * PATCH + pi1 * PATCH + pjb)) * HH + h1) * WW + w8;

    if ((unsigned)r2 >= (unsigned)HH) {
        // x2 row OOB: these (h,pi) outputs are zero for ALL taps. No barriers run.
        float4 zv = make_float4(0.f, 0.f, 0.f, 0.f);
        if (active) {
#pragma unroll
            for (int j = 0; j < 2; j++) {
                if (j == 0 ? st0 : st1) {
                    *(float4*)(out0 + (size_t)j * CSTR)     = zv;
                    *(float4*)(out0 + (size_t)j * CSTR + 4) = zv;
                    if (has1) {
                        *(float4*)(out1 + (size_t)j * CSTR)     = zv;
                        *(float4*)(out1 + (size_t)j * CSTR + 4) = zv;
                    }
                }
            }
        }
        return;
    }

    // Prologue: zero never-staged OOB slots of all 4 rows (2 buf x 2 ch).
    if (tid < 40) {
        const int rr = tid / 10, g = tid % 10;
        const int slot = (g < 5) ? g : (256 + g);   // {0..4, 261..265}
        *(float4*)(sx2 + rr * ROWF + 4 * slot) = make_float4(0.f, 0.f, 0.f, 0.f);
    }

    // Window granule base: padded col p = 8*tw + 2*pjb + (k + 2j); gb = 2tw + pjb/2.
    // Inactive waves clamp to a safe base (they read nothing meaningful anyway).
    const int g0 = active ? (2 * tw + 2 * z + th2) : (2 * tw);
    int ps0 = 4 * swz(g0), ps1 = 4 * swz(g0 + 1), ps2 = 4 * swz(g0 + 2);

    const float* x2base = x2 + ((size_t)(b * CC) * HH + r2) * WW;
    const float* x1p0   = x1 + ((size_t)(b * CC) * HH + h0) * WW + w8;
    const float* x1p1   = has1 ? (x1p0 + 2 * WW) : x1p0;   // clamp: unused if !has1

    stage_dma(x2base, sx2, tid);     // chunk 0 -> buf 0
    __syncthreads();                 // drains DMA + prologue zeros

    float acc0[2][8], acc1[2][8];
#pragma unroll
    for (int j = 0; j < 2; j++)
#pragma unroll
        for (int k = 0; k < 8; k++) { acc0[j][k] = 0.f; acc1[j][k] = 0.f; }

    for (int p = 0; p < NP; p++) {
        if (p + 1 < NP)   // issue next chunk's DMA before computing this one
            stage_dma(x2base + (size_t)(p + 1) * CHUNKC * CSTR,
                      sx2 + ((p + 1) & 1) * BUFF, tid);
        if (active) {
            const float* buf = sx2 + (p & 1) * BUFF;
#pragma unroll
            for (int c = 0; c < CHUNKC; c++) {
                const float* row = buf + c * ROWF;
                float win[12];
                *(float4*)&win[0] = *(const float4*)(row + ps0);
                *(float4*)&win[4] = *(const float4*)(row + ps1);
                *(float4*)&win[8] = *(const float4*)(row + ps2);

                const float* xa = x1p0 + (size_t)(CHUNKC * p + c) * CSTR;
                const float* xb = x1p1 + (size_t)(CHUNKC * p + c) * CSTR;
                float4 a00 = *(const float4*)xa, a01 = *(const float4*)(xa + 4);
                float4 a10 = *(const float4*)xb, a11 = *(const float4*)(xb + 4);
                const float a0[8] = {a00.x, a00.y, a00.z, a00.w, a01.x, a01.y, a01.z, a01.w};
                const float a1[8] = {a10.x, a10.y, a10.z, a10.w, a11.x, a11.y, a11.z, a11.w};

                // tap j, output w8+k -> window float k + 2j (static, max 9)
#pragma unroll
                for (int j = 0; j < 2; j++)
#pragma unroll
                    for (int k = 0; k < 8; k++) {
                        const float wv = win[k + 2 * j];
                        acc0[j][k] = fmaf(a0[k], wv, acc0[j][k]);
                        acc1[j][k] = fmaf(a1[k], wv, acc1[j][k]);
                    }
            }
        }
        if (p + 1 < NP) __syncthreads();
    }

    if (!active) return;

    const float inv_c = 1.0f / (float)CC;
#pragma unroll
    for (int j = 0; j < 2; j++) {
        if (j == 0 ? st0 : st1) {
            float4 o0, o1, q0, q1;
            float* po0 = (float*)&o0; float* po1 = (float*)&o1;
            float* pq0 = (float*)&q0; float* pq1 = (float*)&q1;
#pragma unroll
            for (int k = 0; k < 4; k++) {
                float v0 = acc0[j][k]     * inv_c;
                float v1 = acc0[j][4 + k] * inv_c;
                float u0 = acc1[j][k]     * inv_c;
                float u1 = acc1[j][4 + k] * inv_c;
                po0[k] = v0 > 0.f ? v0 : 0.1f * v0;
                po1[k] = v1 > 0.f ? v1 : 0.1f * v1;
                pq0[k] = u0 > 0.f ? u0 : 0.1f * u0;
                pq1[k] = u1 > 0.f ? u1 : 0.1f * u1;
            }
            *(float4*)(out0 + (size_t)j * CSTR)     = o0;
            *(float4*)(out0 + (size_t)j * CSTR + 4) = o1;
            if (has1) {
                *(float4*)(out1 + (size_t)j * CSTR)     = q0;
                *(float4*)(out1 + (size_t)j * CSTR + 4) = q1;
            }
        }
    }
}

extern "C" void kernel_launch(void* const* d_in, const int* in_sizes, int n_in,
                              void* d_out, int out_size, void* d_ws, size_t ws_size,
                              hipStream_t stream) {
    const float* x1 = (const float*)d_in[0];
    const float* x2 = (const float*)d_in[1];
    float* out = (float*)d_out;

    // grid: (r2+20, b*8 + chain-slot, tap-group z). Covers every (h,pi) exactly
    // once (valid r2 -> compute; OOB r2 -> zero-fill), taps 0..20 via z,th2,j.
    dim3 grid(72, BB * 8, 6);
    dim3 block(256, 1, 1);
    corr_kernel<<<grid, block, 0, stream>>>(x1, x2, out);
}